// Round 1
// baseline (3341.982 us; speedup 1.0000x reference)
//
#include <hip/hip_runtime.h>
#include <hip/hip_bf16.h>
#include <cmath>

// Problem constants (folding3 config): B=32, S_out=2048, S_in=512, D=128
#define NB   32
#define SOUT 2048
#define SIN  512

// ---------------------------------------------------------------------------
// pts: faithful port of _sample_2D(m, n) for the 2048 grid points.
// pts[k,0] = xs[iy[k/m]], pts[k,1] = xs[ix[k%m]],
// ix[b] = round(45*b/(m-1)), iy[a] = round(45*a/(n-1)), xs[i] = -0.3 + 0.6*i/45
// ---------------------------------------------------------------------------
__global__ void pts_kernel(const int* __restrict__ mArr, const int* __restrict__ nArr,
                           float* __restrict__ pts) {
  int k = blockIdx.x * blockDim.x + threadIdx.x;
  if (k >= SOUT) return;
  int m = mArr[0], n = nArr[0];
  int b = k % m, a = k / m;
  int ixb = (int)rint(45.0 * (double)b / (double)(m - 1));
  int iya = (int)rint(45.0 * (double)a / (double)(n - 1));
  const float step = 0.6f / 45.0f;
  pts[2 * k + 0] = -0.3f + step * (float)iya;
  pts[2 * k + 1] = -0.3f + step * (float)ixb;
}

// ---------------------------------------------------------------------------
// qc builder: qc[b,i,0:128] = q[b, i%512, :]
//             qc[b,i,128:256] = relu(concat(q_row, pts[i]) @ Wup[130,128] + bup)
// One block = 16 consecutive global rows, 128 threads (one output col each).
// ---------------------------------------------------------------------------
__global__ __launch_bounds__(128) void qc_kernel(
    const float* __restrict__ q, const float* __restrict__ pts,
    const float* __restrict__ Wup, const float* __restrict__ bup,
    float* __restrict__ qc) {
  __shared__ float xs[16][132];  // 130 used, padded
  int tid = threadIdx.x;
  long row0 = (long)blockIdx.x * 16;
  for (int r = 0; r < 16; ++r) {
    long row = row0 + r;
    int b = (int)(row >> 11);          // /2048
    int i = (int)(row & 2047);
    xs[r][tid] = q[((long)b * SIN + (i & 511)) * 128 + tid];
    if (tid < 2) xs[r][128 + tid] = pts[2 * i + tid];
  }
  __syncthreads();
  float acc[16];
#pragma unroll
  for (int r = 0; r < 16; ++r) acc[r] = 0.f;
  for (int k = 0; k < 130; ++k) {
    float w = Wup[k * 128 + tid];
#pragma unroll
    for (int r = 0; r < 16; ++r) acc[r] += xs[r][k] * w;
  }
  float bb = bup[tid];
#pragma unroll
  for (int r = 0; r < 16; ++r) {
    long row = row0 + r;
    qc[row * 256 + tid] = xs[r][tid];
    qc[row * 256 + 128 + tid] = fmaxf(acc[r] + bb, 0.f);
  }
}

// ---------------------------------------------------------------------------
// Generic fp32 GEMM with fused epilogue: acc = A[M,K] @ W[K,N] + bias
//   mode 0: C = relu(acc)
//   mode 1: C = aux - relu(acc)        (pm = p - down(...))
//   mode 2: C = relu(acc) + aux        (out = p2 + p1)
// BM=128, BN=64, BK=16; 256 threads; 8x4 per-thread microtile.
// ---------------------------------------------------------------------------
#define GBM 128
#define GBN 64
#define GBK 16

__global__ __launch_bounds__(256) void relugemm(
    const float* __restrict__ A, const float* __restrict__ W,
    const float* __restrict__ bias, float* __restrict__ C,
    const float* __restrict__ aux,
    int M, int N, int K, int mode) {
  __shared__ float As[GBK][GBM + 8];  // [k][m], 136*4B rows (16B-aligned)
  __shared__ float Bs[GBK][GBN + 8];  // [k][n], 72*4B rows (16B-aligned)
  int tid = threadIdx.x;
  int tx = tid & 15, ty = tid >> 4;
  long row0 = (long)blockIdx.y * GBM;
  int col0 = blockIdx.x * GBN;
  float acc[8][4];
#pragma unroll
  for (int i = 0; i < 8; ++i)
#pragma unroll
    for (int j = 0; j < 4; ++j) acc[i][j] = 0.f;

  for (int k0 = 0; k0 < K; k0 += GBK) {
#pragma unroll
    for (int qq = 0; qq < 2; ++qq) {
      int idx = tid * 2 + qq;          // 0..511
      int r = idx >> 2;                // 0..127
      int kq = (idx & 3) * 4;          // 0,4,8,12
      float4 v = *(const float4*)(A + (row0 + r) * K + k0 + kq);
      As[kq + 0][r] = v.x; As[kq + 1][r] = v.y;
      As[kq + 2][r] = v.z; As[kq + 3][r] = v.w;
    }
    {
      int r = tid >> 4;                // k row 0..15
      int c4 = (tid & 15) * 4;
      *(float4*)&Bs[r][c4] = *(const float4*)(W + (long)(k0 + r) * N + col0 + c4);
    }
    __syncthreads();
#pragma unroll 8
    for (int kk = 0; kk < GBK; ++kk) {
      float4 a0 = *(float4*)&As[kk][ty * 8];
      float4 a1 = *(float4*)&As[kk][ty * 8 + 4];
      float4 bv = *(float4*)&Bs[kk][tx * 4];
      float av[8] = {a0.x, a0.y, a0.z, a0.w, a1.x, a1.y, a1.z, a1.w};
      float bw[4] = {bv.x, bv.y, bv.z, bv.w};
#pragma unroll
      for (int i = 0; i < 8; ++i)
#pragma unroll
        for (int j = 0; j < 4; ++j) acc[i][j] += av[i] * bw[j];
    }
    __syncthreads();
  }

  float4 bv4 = *(const float4*)(bias + col0 + tx * 4);
  float bvals[4] = {bv4.x, bv4.y, bv4.z, bv4.w};
#pragma unroll
  for (int i = 0; i < 8; ++i) {
    long row = row0 + ty * 8 + i;
    long cbase = row * N + col0 + tx * 4;
    float vals[4];
#pragma unroll
    for (int j = 0; j < 4; ++j) vals[j] = fmaxf(acc[i][j] + bvals[j], 0.f);
    if (mode == 1) {
      float4 sv = *(const float4*)(aux + cbase);
      vals[0] = sv.x - vals[0]; vals[1] = sv.y - vals[1];
      vals[2] = sv.z - vals[2]; vals[3] = sv.w - vals[3];
    } else if (mode == 2) {
      float4 sv = *(const float4*)(aux + cbase);
      vals[0] += sv.x; vals[1] += sv.y; vals[2] += sv.z; vals[3] += sv.w;
    }
    float4 o = {vals[0], vals[1], vals[2], vals[3]};
    *(float4*)(C + cbase) = o;
  }
}

// ---------------------------------------------------------------------------
// Fused attention: qc[b, n, :] += (softmax_m(l[n]·h[m]) @ g)[n, :]
// Block = (b, 64 n-rows). Online softmax over 32 m-blocks of 64.
// LDS: L^T, H^T (reused as P^T), G chunk (64 cols), all padded to 68.
// Thread (ty,tx): S rows ty*4+i, S cols tx*4+j; acc[4 rows][4 chunks][4 cols].
// ---------------------------------------------------------------------------
__global__ __launch_bounds__(256) void attn_kernel(
    const float* __restrict__ lmat, const float* __restrict__ hmat,
    const float* __restrict__ gmat, float* __restrict__ qc) {
  __shared__ float LsT[64][68];
  __shared__ float HsT[64][68];  // aliased as P^T after S is computed
  __shared__ float Gs[64][68];
  __shared__ float red[64][17];
  __shared__ float mrow[64], srow_s[64], scale_s[64];

  int tid = threadIdx.x;
  int tx = tid & 15, ty = tid >> 4;
  int b = blockIdx.y, nb = blockIdx.x;

  // load L^T: LsT[k][r] = l[b, nb*64+r, k]
  long lbase = ((long)b * SOUT + nb * 64) * 64;
#pragma unroll
  for (int qq = 0; qq < 4; ++qq) {
    int idx = tid * 4 + qq;
    int r = idx >> 4;
    int k4 = (idx & 15) * 4;
    float4 v = *(const float4*)(lmat + lbase + (long)r * 64 + k4);
    LsT[k4 + 0][r] = v.x; LsT[k4 + 1][r] = v.y;
    LsT[k4 + 2][r] = v.z; LsT[k4 + 3][r] = v.w;
  }
  if (tid < 64) { mrow[tid] = -INFINITY; srow_s[tid] = 0.f; }

  float acc[4][4][4];
#pragma unroll
  for (int i = 0; i < 4; ++i)
#pragma unroll
    for (int c = 0; c < 4; ++c)
#pragma unroll
      for (int j = 0; j < 4; ++j) acc[i][c][j] = 0.f;

  for (int mb = 0; mb < 32; ++mb) {
    __syncthreads();  // protect HsT/P^T, Gs, red, scale_s from previous iter
    long hbase = ((long)b * SOUT + mb * 64) * 64;
#pragma unroll
    for (int qq = 0; qq < 4; ++qq) {
      int idx = tid * 4 + qq;
      int r = idx >> 4;
      int k4 = (idx & 15) * 4;
      float4 v = *(const float4*)(hmat + hbase + (long)r * 64 + k4);
      HsT[k4 + 0][r] = v.x; HsT[k4 + 1][r] = v.y;
      HsT[k4 + 2][r] = v.z; HsT[k4 + 3][r] = v.w;
    }
    __syncthreads();

    // S = L_blk @ H_blk^T  (64x64, K=64)
    float s[4][4];
#pragma unroll
    for (int i = 0; i < 4; ++i)
#pragma unroll
      for (int j = 0; j < 4; ++j) s[i][j] = 0.f;
#pragma unroll 8
    for (int kk = 0; kk < 64; ++kk) {
      float4 a = *(float4*)&LsT[kk][ty * 4];
      float4 h4 = *(float4*)&HsT[kk][tx * 4];
      float av[4] = {a.x, a.y, a.z, a.w};
      float hv[4] = {h4.x, h4.y, h4.z, h4.w};
#pragma unroll
      for (int i = 0; i < 4; ++i)
#pragma unroll
        for (int j = 0; j < 4; ++j) s[i][j] += av[i] * hv[j];
    }

    // partial row max
#pragma unroll
    for (int i = 0; i < 4; ++i) {
      float pm4 = fmaxf(fmaxf(s[i][0], s[i][1]), fmaxf(s[i][2], s[i][3]));
      red[ty * 4 + i][tx] = pm4;
    }
    __syncthreads();
    if (tid < 64) {
      float bm = red[tid][0];
#pragma unroll
      for (int t = 1; t < 16; ++t) bm = fmaxf(bm, red[tid][t]);
      float om = mrow[tid];
      float nm = fmaxf(om, bm);
      mrow[tid] = nm;
      scale_s[tid] = __expf(om - nm);  // exp(-inf)=0 on first block
    }
    __syncthreads();

    // P = exp(S - m_new); write P^T into HsT; partial row sums
    float psum[4] = {0.f, 0.f, 0.f, 0.f};
#pragma unroll
    for (int i = 0; i < 4; ++i) {
      float nm = mrow[ty * 4 + i];
#pragma unroll
      for (int j = 0; j < 4; ++j) {
        float pv = __expf(s[i][j] - nm);
        psum[i] += pv;
        HsT[tx * 4 + j][ty * 4 + i] = pv;  // P^T[m][n]
      }
    }
#pragma unroll
    for (int i = 0; i < 4; ++i) red[ty * 4 + i][tx] = psum[i];

    // rescale accumulator
#pragma unroll
    for (int i = 0; i < 4; ++i) {
      float sc = scale_s[ty * 4 + i];
#pragma unroll
      for (int c = 0; c < 4; ++c)
#pragma unroll
        for (int j = 0; j < 4; ++j) acc[i][c][j] *= sc;
    }
    __syncthreads();
    if (tid < 64) {
      float bs = 0.f;
#pragma unroll
      for (int t = 0; t < 16; ++t) bs += red[tid][t];
      srow_s[tid] = srow_s[tid] * scale_s[tid] + bs;
    }

    // acc += P @ G, in 4 chunks of 64 cols staged in LDS
    long gbase = ((long)b * SOUT + mb * 64) * 256;
#pragma unroll
    for (int ch = 0; ch < 4; ++ch) {
      __syncthreads();  // protect Gs from previous readers
#pragma unroll
      for (int qq = 0; qq < 4; ++qq) {
        int idx = tid * 4 + qq;
        int r = idx >> 4;
        int c4 = (idx & 15) * 4;
        *(float4*)&Gs[r][c4] =
            *(const float4*)(gmat + gbase + (long)r * 256 + ch * 64 + c4);
      }
      __syncthreads();
#pragma unroll 8
      for (int kk = 0; kk < 64; ++kk) {
        float4 pv4 = *(float4*)&HsT[kk][ty * 4];  // P^T
        float4 gv4 = *(float4*)&Gs[kk][tx * 4];
        float pv[4] = {pv4.x, pv4.y, pv4.z, pv4.w};
        float gv[4] = {gv4.x, gv4.y, gv4.z, gv4.w};
#pragma unroll
        for (int i = 0; i < 4; ++i)
#pragma unroll
          for (int j = 0; j < 4; ++j) acc[i][ch][j] += pv[i] * gv[j];
      }
    }
  }
  __syncthreads();

  // qc += acc / srow  (in place; attention output added to residual input qc)
  long qbase = ((long)b * SOUT + nb * 64) * 256;
#pragma unroll
  for (int i = 0; i < 4; ++i) {
    float inv = 1.0f / srow_s[ty * 4 + i];
#pragma unroll
    for (int ch = 0; ch < 4; ++ch) {
      long addr = qbase + (long)(ty * 4 + i) * 256 + ch * 64 + tx * 4;
      float4 cur = *(const float4*)(qc + addr);
      cur.x += acc[i][ch][0] * inv;
      cur.y += acc[i][ch][1] * inv;
      cur.z += acc[i][ch][2] * inv;
      cur.w += acc[i][ch][3] * inv;
      *(float4*)(qc + addr) = cur;
    }
  }
}

// ---------------------------------------------------------------------------
extern "C" void kernel_launch(void* const* d_in, const int* in_sizes, int n_in,
                              void* d_out, int out_size, void* d_ws, size_t ws_size,
                              hipStream_t stream) {
  (void)in_sizes; (void)n_in; (void)out_size; (void)ws_size;
  const float* p   = (const float*)d_in[0];
  const float* Wh  = (const float*)d_in[1];
  const float* bh  = (const float*)d_in[2];
  const float* Wl  = (const float*)d_in[3];
  const float* bl  = (const float*)d_in[4];
  const float* Wg  = (const float*)d_in[5];
  const float* bg  = (const float*)d_in[6];
  const float* Wf  = (const float*)d_in[7];
  const float* bf  = (const float*)d_in[8];
  const float* Wup = (const float*)d_in[9];
  const float* bup = (const float*)d_in[10];
  const float* Wd1 = (const float*)d_in[11];
  const float* bd1 = (const float*)d_in[12];
  const float* Wd2 = (const float*)d_in[13];
  const float* bd2 = (const float*)d_in[14];
  const int* mArr  = (const int*)d_in[15];
  const int* nArr  = (const int*)d_in[16];
  float* out = (float*)d_out;

  // workspace layout (floats); total = 56,627,200 floats ~= 216 MB
  float* ws   = (float*)d_ws;
  float* pts  = ws;                       // 4096
  float* qc   = ws + 4096;                // 32*2048*256 = 16,777,216
  float* hbuf = qc + 16777216;            // 32*2048*64  =  4,194,304
  float* lbuf = hbuf + 4194304;           //  4,194,304
  float* gbuf = lbuf + 4194304;           // 16,777,216
  float* p1   = gbuf + 16777216;          // 32*2048*128 =  8,388,608
  float* d1   = p1 + 8388608;             // 32*512*256  =  4,194,304
  float* pm   = d1 + 4194304;             // 32*512*128  =  2,097,152

  pts_kernel<<<8, 256, 0, stream>>>(mArr, nArr, pts);

  // ---------------- up #1: p1 = up(p) ----------------
  qc_kernel<<<4096, 128, 0, stream>>>(p, pts, Wup, bup, qc);
  relugemm<<<dim3(1, 512), 256, 0, stream>>>(qc, Wh, bh, hbuf, nullptr, 65536, 64, 256, 0);
  relugemm<<<dim3(1, 512), 256, 0, stream>>>(qc, Wl, bl, lbuf, nullptr, 65536, 64, 256, 0);
  relugemm<<<dim3(4, 512), 256, 0, stream>>>(qc, Wg, bg, gbuf, nullptr, 65536, 256, 256, 0);
  attn_kernel<<<dim3(32, 32), 256, 0, stream>>>(lbuf, hbuf, gbuf, qc);
  relugemm<<<dim3(2, 512), 256, 0, stream>>>(qc, Wf, bf, p1, nullptr, 65536, 128, 256, 0);

  // ---------------- down: pm = p - down(p1) ----------------
  // reshape [32,2048,128] -> [16384,512] is a pure view (row-major)
  relugemm<<<dim3(4, 128), 256, 0, stream>>>(p1, Wd1, bd1, d1, nullptr, 16384, 256, 512, 0);
  relugemm<<<dim3(2, 128), 256, 0, stream>>>(d1, Wd2, bd2, pm, p, 16384, 128, 256, 1);

  // ---------------- up #2 + final add: out = up(pm) + p1 ----------------
  qc_kernel<<<4096, 128, 0, stream>>>(pm, pts, Wup, bup, qc);
  relugemm<<<dim3(1, 512), 256, 0, stream>>>(qc, Wh, bh, hbuf, nullptr, 65536, 64, 256, 0);
  relugemm<<<dim3(1, 512), 256, 0, stream>>>(qc, Wl, bl, lbuf, nullptr, 65536, 64, 256, 0);
  relugemm<<<dim3(4, 512), 256, 0, stream>>>(qc, Wg, bg, gbuf, nullptr, 65536, 256, 256, 0);
  attn_kernel<<<dim3(32, 32), 256, 0, stream>>>(lbuf, hbuf, gbuf, qc);
  relugemm<<<dim3(2, 512), 256, 0, stream>>>(qc, Wf, bf, out, p1, 65536, 128, 256, 2);
}

// Round 2
// 1402.105 us; speedup vs baseline: 2.3835x; 2.3835x over previous
//
#include <hip/hip_runtime.h>
#include <hip/hip_bf16.h>
#include <cmath>

// Problem constants (folding3 config): B=32, S_out=2048, S_in=512, D=128
#define NB   32
#define SOUT 2048
#define SIN  512

typedef __attribute__((ext_vector_type(8))) short bhalf8;   // 8 bf16 (4 VGPRs)
typedef __attribute__((ext_vector_type(4))) float f32x4;

__device__ inline ushort f2b(float x) {                     // f32 -> bf16 RNE
  union { float f; unsigned u; } v; v.f = x;
  unsigned r = v.u + 0x7FFFu + ((v.u >> 16) & 1u);
  return (ushort)(r >> 16);
}

__device__ inline void gload16(const void* g, void* l) {    // async global->LDS, 16B/lane
  __builtin_amdgcn_global_load_lds(
      (const __attribute__((address_space(1))) void*)g,
      (__attribute__((address_space(3))) void*)l, 16, 0, 0);
}

// ---------------------------------------------------------------------------
// pts: faithful port of _sample_2D(m, n)
// ---------------------------------------------------------------------------
__global__ void pts_kernel(const int* __restrict__ mArr, const int* __restrict__ nArr,
                           float* __restrict__ pts) {
  int k = blockIdx.x * blockDim.x + threadIdx.x;
  if (k >= SOUT) return;
  int m = mArr[0], n = nArr[0];
  int b = k % m, a = k / m;
  int ixb = (int)rint(45.0 * (double)b / (double)(m - 1));
  int iya = (int)rint(45.0 * (double)a / (double)(n - 1));
  const float step = 0.6f / 45.0f;
  pts[2 * k + 0] = -0.3f + step * (float)iya;
  pts[2 * k + 1] = -0.3f + step * (float)ixb;
}

// ---------------------------------------------------------------------------
// qc builder: qc[b,i,0:128] = q[b, i%512, :]
//             qc[b,i,128:256] = relu(concat(q_row, pts[i]) @ Wup[130,128] + bup)
// ---------------------------------------------------------------------------
__global__ __launch_bounds__(128) void qc_kernel(
    const float* __restrict__ q, const float* __restrict__ pts,
    const float* __restrict__ Wup, const float* __restrict__ bup,
    float* __restrict__ qc) {
  __shared__ float xs[16][132];
  int tid = threadIdx.x;
  long row0 = (long)blockIdx.x * 16;
  for (int r = 0; r < 16; ++r) {
    long row = row0 + r;
    int b = (int)(row >> 11);
    int i = (int)(row & 2047);
    xs[r][tid] = q[((long)b * SIN + (i & 511)) * 128 + tid];
    if (tid < 2) xs[r][128 + tid] = pts[2 * i + tid];
  }
  __syncthreads();
  float acc[16];
#pragma unroll
  for (int r = 0; r < 16; ++r) acc[r] = 0.f;
  for (int k = 0; k < 130; ++k) {
    float w = Wup[k * 128 + tid];
#pragma unroll
    for (int r = 0; r < 16; ++r) acc[r] += xs[r][k] * w;
  }
  float bb = bup[tid];
#pragma unroll
  for (int r = 0; r < 16; ++r) {
    long row = row0 + r;
    qc[row * 256 + tid] = xs[r][tid];
    qc[row * 256 + 128 + tid] = fmaxf(acc[r] + bb, 0.f);
  }
}

// ---------------------------------------------------------------------------
// Generic fp32 GEMM, templated epilogue: acc = A[M,K] @ W[K,N] + bias
//   MODE 0: C(f32) = relu(acc)
//   MODE 1: C(f32) = aux - relu(acc)
//   MODE 2: C(f32) = relu(acc) + aux
//   MODE 3: C(bf16 row-major) = relu(acc)
//   MODE 4: C(bf16, per-batch transposed [b][N][2048]) = relu(acc)
// BM=128, BN=64, BK=16; 256 threads; 8x4 microtile.
// ---------------------------------------------------------------------------
#define GBM 128
#define GBN 64
#define GBK 16

template <int MODE>
__global__ __launch_bounds__(256) void relugemm(
    const float* __restrict__ A, const float* __restrict__ W,
    const float* __restrict__ bias, void* __restrict__ Cv,
    const float* __restrict__ aux,
    int M, int N, int K) {
  __shared__ float As[GBK][GBM + 8];
  __shared__ float Bs[GBK][GBN + 8];
  int tid = threadIdx.x;
  int tx = tid & 15, ty = tid >> 4;
  long row0 = (long)blockIdx.y * GBM;
  int col0 = blockIdx.x * GBN;
  float acc[8][4];
#pragma unroll
  for (int i = 0; i < 8; ++i)
#pragma unroll
    for (int j = 0; j < 4; ++j) acc[i][j] = 0.f;

  for (int k0 = 0; k0 < K; k0 += GBK) {
#pragma unroll
    for (int qq = 0; qq < 2; ++qq) {
      int idx = tid * 2 + qq;
      int r = idx >> 2;
      int kq = (idx & 3) * 4;
      float4 v = *(const float4*)(A + (row0 + r) * K + k0 + kq);
      As[kq + 0][r] = v.x; As[kq + 1][r] = v.y;
      As[kq + 2][r] = v.z; As[kq + 3][r] = v.w;
    }
    {
      int r = tid >> 4;
      int c4 = (tid & 15) * 4;
      *(float4*)&Bs[r][c4] = *(const float4*)(W + (long)(k0 + r) * N + col0 + c4);
    }
    __syncthreads();
#pragma unroll 8
    for (int kk = 0; kk < GBK; ++kk) {
      float4 a0 = *(float4*)&As[kk][ty * 8];
      float4 a1 = *(float4*)&As[kk][ty * 8 + 4];
      float4 bv = *(float4*)&Bs[kk][tx * 4];
      float av[8] = {a0.x, a0.y, a0.z, a0.w, a1.x, a1.y, a1.z, a1.w};
      float bw[4] = {bv.x, bv.y, bv.z, bv.w};
#pragma unroll
      for (int i = 0; i < 8; ++i)
#pragma unroll
        for (int j = 0; j < 4; ++j) acc[i][j] += av[i] * bw[j];
    }
    __syncthreads();
  }

  float4 bv4 = *(const float4*)(bias + col0 + tx * 4);
  float bvals[4] = {bv4.x, bv4.y, bv4.z, bv4.w};

  if (MODE == 4) {
    // per-batch transposed bf16 store: C[b][d][m], rows never cross batch
    int bb = (int)(row0 >> 11);
    int mloc = (int)(row0 & 2047) + ty * 8;
    ushort* C = (ushort*)Cv;
#pragma unroll
    for (int j = 0; j < 4; ++j) {
      int d = col0 + tx * 4 + j;
      ushort u[8];
#pragma unroll
      for (int i = 0; i < 8; ++i) u[i] = f2b(fmaxf(acc[i][j] + bvals[j], 0.f));
      ushort* dst = C + ((long)bb * 256 + d) * 2048 + mloc;
      ushort4 lo, hi;
      lo.x = u[0]; lo.y = u[1]; lo.z = u[2]; lo.w = u[3];
      hi.x = u[4]; hi.y = u[5]; hi.z = u[6]; hi.w = u[7];
      *(ushort4*)dst = lo;
      *(ushort4*)(dst + 4) = hi;
    }
    return;
  }

#pragma unroll
  for (int i = 0; i < 8; ++i) {
    long row = row0 + ty * 8 + i;
    long cbase = row * N + col0 + tx * 4;
    float vals[4];
#pragma unroll
    for (int j = 0; j < 4; ++j) vals[j] = fmaxf(acc[i][j] + bvals[j], 0.f);
    if (MODE == 1) {
      float4 sv = *(const float4*)(aux + cbase);
      vals[0] = sv.x - vals[0]; vals[1] = sv.y - vals[1];
      vals[2] = sv.z - vals[2]; vals[3] = sv.w - vals[3];
    } else if (MODE == 2) {
      float4 sv = *(const float4*)(aux + cbase);
      vals[0] += sv.x; vals[1] += sv.y; vals[2] += sv.z; vals[3] += sv.w;
    }
    if (MODE == 3) {
      ushort4 o4;
      o4.x = f2b(vals[0]); o4.y = f2b(vals[1]);
      o4.z = f2b(vals[2]); o4.w = f2b(vals[3]);
      *(ushort4*)((ushort*)Cv + cbase) = o4;
    } else {
      float4 o = {vals[0], vals[1], vals[2], vals[3]};
      *(float4*)((float*)Cv + cbase) = o;
    }
  }
}

// ---------------------------------------------------------------------------
// MFMA flash attention: qc[b, n, :] += softmax_m(l[n]·h[m]) @ g
// Inputs: l,h bf16 [b][2048][64]; gT bf16 [b][256][2048]; qc f32 [b][2048][256].
// Block = (nb, b): 64 q-rows, 256 threads = 4 waves.
// QK row-split (wave w owns S rows 16w..16w+15); PV col-split (wave w owns
// O cols 64w..64w+63 of all 64 rows) so waves share P/G^T fragments.
// LDS tiles XOR-swizzled (byte ^= (row&7)<<4), staged via global_load_lds
// with pre-swizzled global source addresses.
// ---------------------------------------------------------------------------
__global__ __launch_bounds__(256) void attn_kernel(
    const ushort* __restrict__ lmat, const ushort* __restrict__ hmat,
    const ushort* __restrict__ gtm, float* __restrict__ qc) {
  __shared__ alignas(16) ushort Lt[64 * 64];
  __shared__ alignas(16) ushort Ht[64 * 64];
  __shared__ alignas(16) ushort Gt[256 * 64];
  __shared__ alignas(16) ushort Pt[64 * 72];   // padded stride 72
  __shared__ alignas(16) float rowscale[64];

  const int tid = threadIdx.x;
  const int w = tid >> 6;          // wave 0..3
  const int lane = tid & 63;
  const int g = lane >> 4;         // 0..3
  const int c = lane & 15;         // 0..15
  const int b = blockIdx.y, nb = blockIdx.x;

  // ---- stage L tile ----
  {
    const char* base = (const char*)(lmat + ((long)b * SOUT + nb * 64) * 64);
#pragma unroll
    for (int it = 0; it < 2; ++it) {
      int o = it * 4096 + w * 1024 + lane * 16;
      int row = o >> 7, cb = o & 127;
      gload16(base + row * 128 + (cb ^ ((row & 7) << 4)),
              (char*)Lt + it * 4096 + w * 1024);
    }
  }
  float mold[4], srow[4];
#pragma unroll
  for (int r = 0; r < 4; ++r) { mold[r] = -INFINITY; srow[r] = 0.f; }
  f32x4 oacc[4][4];
#pragma unroll
  for (int i = 0; i < 4; ++i)
#pragma unroll
    for (int t = 0; t < 4; ++t) oacc[i][t] = (f32x4){0.f, 0.f, 0.f, 0.f};

  __syncthreads();  // L tile resident

  // hoist L A-fragments (rows 16w+c, k = 8g + 32s)
  bhalf8 la[2];
  {
    int row = 16 * w + c;
    int rb = row * 128, sw = (row & 7) << 4;
#pragma unroll
    for (int s = 0; s < 2; ++s)
      la[s] = *(const bhalf8*)((const char*)Lt + rb + ((s * 64 + g * 16) ^ sw));
  }

  for (int mb = 0; mb < 32; ++mb) {
    // ---- stage H tile (8KB) and G^T tile (32KB) ----
    {
      const char* hbase = (const char*)(hmat + ((long)b * SOUT + mb * 64) * 64);
#pragma unroll
      for (int it = 0; it < 2; ++it) {
        int o = it * 4096 + w * 1024 + lane * 16;
        int row = o >> 7, cb = o & 127;
        gload16(hbase + row * 128 + (cb ^ ((row & 7) << 4)),
                (char*)Ht + it * 4096 + w * 1024);
      }
      const char* gbase = (const char*)(gtm + (long)b * 256 * SOUT + mb * 64);
#pragma unroll
      for (int it = 0; it < 8; ++it) {
        int o = it * 4096 + w * 1024 + lane * 16;
        int row = o >> 7, cb = o & 127;
        gload16(gbase + (long)row * (SOUT * 2) + (cb ^ ((row & 7) << 4)),
                (char*)Gt + it * 4096 + w * 1024);
      }
    }
    __syncthreads();  // (b) tiles ready (barrier drains vmcnt)

    // ---- QK^T: S[16 rows of wave][64] ----
    f32x4 sacc[4];
#pragma unroll
    for (int j = 0; j < 4; ++j) sacc[j] = (f32x4){0.f, 0.f, 0.f, 0.f};
#pragma unroll
    for (int j = 0; j < 4; ++j) {
      int row = 16 * j + c;
      int rb = row * 128, sw = (row & 7) << 4;
#pragma unroll
      for (int s = 0; s < 2; ++s) {
        bhalf8 hb = *(const bhalf8*)((const char*)Ht + rb + ((s * 64 + g * 16) ^ sw));
        sacc[j] = __builtin_amdgcn_mfma_f32_16x16x32_bf16(la[s], hb, sacc[j], 0, 0, 0);
      }
    }

    // ---- online softmax (rows 16w+4g+r; cols spread over j and 16 lanes) ----
    float mloc[4];
#pragma unroll
    for (int r = 0; r < 4; ++r)
      mloc[r] = fmaxf(fmaxf(sacc[0][r], sacc[1][r]), fmaxf(sacc[2][r], sacc[3][r]));
#pragma unroll
    for (int off = 1; off < 16; off <<= 1)
#pragma unroll
      for (int r = 0; r < 4; ++r)
        mloc[r] = fmaxf(mloc[r], __shfl_xor(mloc[r], off));
    float scl[4], mnew[4], psum[4];
#pragma unroll
    for (int r = 0; r < 4; ++r) {
      mnew[r] = fmaxf(mold[r], mloc[r]);
      scl[r] = __expf(mold[r] - mnew[r]);   // first iter: exp(-inf)=0
      psum[r] = 0.f;
    }
    float pvv[4][4];
#pragma unroll
    for (int j = 0; j < 4; ++j)
#pragma unroll
      for (int r = 0; r < 4; ++r) {
        float e = __expf(sacc[j][r] - mnew[r]);
        pvv[j][r] = e; psum[r] += e;
      }
#pragma unroll
    for (int off = 1; off < 16; off <<= 1)
#pragma unroll
      for (int r = 0; r < 4; ++r) psum[r] += __shfl_xor(psum[r], off);
#pragma unroll
    for (int r = 0; r < 4; ++r) {
      srow[r] = srow[r] * scl[r] + psum[r];
      mold[r] = mnew[r];
    }
    // write P (bf16) and per-row scale
#pragma unroll
    for (int j = 0; j < 4; ++j)
#pragma unroll
      for (int r = 0; r < 4; ++r)
        Pt[(16 * w + 4 * g + r) * 72 + 16 * j + c] = f2b(pvv[j][r]);
    if (c == 0) {
      f32x4 s4 = {scl[0], scl[1], scl[2], scl[3]};
      *(f32x4*)&rowscale[16 * w + 4 * g] = s4;
    }
    __syncthreads();  // (c) P + scales visible

    // ---- rescale O by this iter's scale (all 64 rows, own col slice) ----
#pragma unroll
    for (int i = 0; i < 4; ++i) {
      f32x4 s4 = *(const f32x4*)&rowscale[16 * i + 4 * g];
#pragma unroll
      for (int t = 0; t < 4; ++t) {
        oacc[i][t][0] *= s4[0]; oacc[i][t][1] *= s4[1];
        oacc[i][t][2] *= s4[2]; oacc[i][t][3] *= s4[3];
      }
    }

    // ---- PV: O[64 rows][cols 64w..64w+63] += P @ G ----
#pragma unroll
    for (int s2 = 0; s2 < 2; ++s2) {
      bhalf8 pa[4];
#pragma unroll
      for (int i = 0; i < 4; ++i)
        pa[i] = *(const bhalf8*)((const char*)Pt +
                                 ((16 * i + c) * 72 + s2 * 32 + g * 8) * 2);
#pragma unroll
      for (int t = 0; t < 4; ++t) {
        int row = 64 * w + 16 * t + c;   // G^T row = d
        bhalf8 gb = *(const bhalf8*)((const char*)Gt + row * 128 +
                                     ((s2 * 64 + g * 16) ^ ((row & 7) << 4)));
#pragma unroll
        for (int i = 0; i < 4; ++i)
          oacc[i][t] = __builtin_amdgcn_mfma_f32_16x16x32_bf16(pa[i], gb, oacc[i][t], 0, 0, 0);
      }
    }
    __syncthreads();  // (a) all reads of Ht/Gt/Pt/rowscale done
  }

  // ---- epilogue: qc += O / srow ----
  if (c == 0) {
    f32x4 s4 = {srow[0], srow[1], srow[2], srow[3]};
    *(f32x4*)&rowscale[16 * w + 4 * g] = s4;
  }
  __syncthreads();
  long qbase = ((long)b * SOUT + nb * 64) * 256;
#pragma unroll
  for (int i = 0; i < 4; ++i) {
    f32x4 s4 = *(const f32x4*)&rowscale[16 * i + 4 * g];
#pragma unroll
    for (int r = 0; r < 4; ++r) {
      float inv = 1.0f / s4[r];
      long rb = qbase + (long)(16 * i + 4 * g + r) * 256 + 64 * w + c;
#pragma unroll
      for (int t = 0; t < 4; ++t) {
        float* p = qc + rb + 16 * t;
        *p += oacc[i][t][r] * inv;
      }
    }
  }
}

// ---------------------------------------------------------------------------
extern "C" void kernel_launch(void* const* d_in, const int* in_sizes, int n_in,
                              void* d_out, int out_size, void* d_ws, size_t ws_size,
                              hipStream_t stream) {
  (void)in_sizes; (void)n_in; (void)out_size; (void)ws_size;
  const float* p   = (const float*)d_in[0];
  const float* Wh  = (const float*)d_in[1];
  const float* bh  = (const float*)d_in[2];
  const float* Wl  = (const float*)d_in[3];
  const float* bl  = (const float*)d_in[4];
  const float* Wg  = (const float*)d_in[5];
  const float* bg  = (const float*)d_in[6];
  const float* Wf  = (const float*)d_in[7];
  const float* bf  = (const float*)d_in[8];
  const float* Wup = (const float*)d_in[9];
  const float* bup = (const float*)d_in[10];
  const float* Wd1 = (const float*)d_in[11];
  const float* bd1 = (const float*)d_in[12];
  const float* Wd2 = (const float*)d_in[13];
  const float* bd2 = (const float*)d_in[14];
  const int* mArr  = (const int*)d_in[15];
  const int* nArr  = (const int*)d_in[16];
  float* out = (float*)d_out;

  // workspace layout
  float* ws   = (float*)d_ws;
  float* pts  = ws;                        // 4096 f32
  float* qc   = ws + 4096;                 // 16,777,216 f32
  float* p1   = qc + 16777216;             //  8,388,608 f32
  float* d1   = p1 + 8388608;              //  4,194,304 f32
  float* pm   = d1 + 4194304;              //  2,097,152 f32
  ushort* hb  = (ushort*)(pm + 2097152);   //  4,194,304 bf16
  ushort* lb  = hb + 4194304;              //  4,194,304 bf16
  ushort* gt  = lb + 4194304;              // 16,777,216 bf16 (transposed [b][256][2048])

  pts_kernel<<<8, 256, 0, stream>>>(mArr, nArr, pts);

  // ---------------- up #1: p1 = up(p) ----------------
  qc_kernel<<<4096, 128, 0, stream>>>(p, pts, Wup, bup, qc);
  relugemm<3><<<dim3(1, 512), 256, 0, stream>>>(qc, Wh, bh, hb, nullptr, 65536, 64, 256);
  relugemm<3><<<dim3(1, 512), 256, 0, stream>>>(qc, Wl, bl, lb, nullptr, 65536, 64, 256);
  relugemm<4><<<dim3(4, 512), 256, 0, stream>>>(qc, Wg, bg, gt, nullptr, 65536, 256, 256);
  attn_kernel<<<dim3(32, 32), 256, 0, stream>>>(lb, hb, gt, qc);
  relugemm<0><<<dim3(2, 512), 256, 0, stream>>>(qc, Wf, bf, p1, nullptr, 65536, 128, 256);

  // ---------------- down: pm = p - down(p1) ----------------
  relugemm<0><<<dim3(4, 128), 256, 0, stream>>>(p1, Wd1, bd1, d1, nullptr, 16384, 256, 512);
  relugemm<1><<<dim3(2, 128), 256, 0, stream>>>(d1, Wd2, bd2, pm, p, 16384, 128, 256);

  // ---------------- up #2 + final add: out = up(pm) + p1 ----------------
  qc_kernel<<<4096, 128, 0, stream>>>(pm, pts, Wup, bup, qc);
  relugemm<3><<<dim3(1, 512), 256, 0, stream>>>(qc, Wh, bh, hb, nullptr, 65536, 64, 256);
  relugemm<3><<<dim3(1, 512), 256, 0, stream>>>(qc, Wl, bl, lb, nullptr, 65536, 64, 256);
  relugemm<4><<<dim3(4, 512), 256, 0, stream>>>(qc, Wg, bg, gt, nullptr, 65536, 256, 256);
  attn_kernel<<<dim3(32, 32), 256, 0, stream>>>(lb, hb, gt, qc);
  relugemm<2><<<dim3(2, 512), 256, 0, stream>>>(qc, Wf, bf, out, p1, 65536, 128, 256);
}

// Round 3
// 799.122 us; speedup vs baseline: 4.1821x; 1.7546x over previous
//
#include <hip/hip_runtime.h>
#include <hip/hip_bf16.h>
#include <cmath>

#define NB   32
#define SOUT 2048
#define SIN  512

typedef __attribute__((ext_vector_type(8))) short bhalf8;   // 8 bf16 (4 VGPRs)
typedef __attribute__((ext_vector_type(4))) float f32x4;

__device__ inline ushort f2b(float x) {                     // f32 -> bf16 RNE
  union { float f; unsigned u; } v; v.f = x;
  unsigned r = v.u + 0x7FFFu + ((v.u >> 16) & 1u);
  return (ushort)(r >> 16);
}

__device__ inline void gload16(const void* g, void* l) {    // async global->LDS, 16B/lane
  __builtin_amdgcn_global_load_lds(
      (const __attribute__((address_space(1))) void*)g,
      (__attribute__((address_space(3))) void*)l, 16, 0, 0);
}

// ---------------------------------------------------------------------------
// pts
// ---------------------------------------------------------------------------
__global__ void pts_kernel(const int* __restrict__ mArr, const int* __restrict__ nArr,
                           float* __restrict__ pts) {
  int k = blockIdx.x * blockDim.x + threadIdx.x;
  if (k >= SOUT) return;
  int m = mArr[0], n = nArr[0];
  int b = k % m, a = k / m;
  int ixb = (int)rint(45.0 * (double)b / (double)(m - 1));
  int iya = (int)rint(45.0 * (double)a / (double)(n - 1));
  const float step = 0.6f / 45.0f;
  pts[2 * k + 0] = -0.3f + step * (float)iya;
  pts[2 * k + 1] = -0.3f + step * (float)ixb;
}

// ---------------------------------------------------------------------------
// wconv: transpose-convert 6 weight matrices W[K,N] f32 -> Wt[N,K] bf16.
// blockIdx.y selects matrix.
// ---------------------------------------------------------------------------
__global__ __launch_bounds__(256) void wconv_kernel(
    const float* __restrict__ Wh, const float* __restrict__ Wl,
    const float* __restrict__ Wg, const float* __restrict__ Wf,
    const float* __restrict__ Wd1, const float* __restrict__ Wd2,
    ushort* __restrict__ dst) {
  const int which = blockIdx.y;
  const float* src; int K, N; long off;
  switch (which) {
    case 0: src = Wh;  K = 256; N = 64;  off = 0;      break;
    case 1: src = Wl;  K = 256; N = 64;  off = 16384;  break;
    case 2: src = Wg;  K = 256; N = 256; off = 32768;  break;
    case 3: src = Wf;  K = 256; N = 128; off = 98304;  break;
    case 4: src = Wd1; K = 512; N = 256; off = 131072; break;
    default:src = Wd2; K = 256; N = 128; off = 262144; break;
  }
  int idx = blockIdx.x * 256 + threadIdx.x;
  if (idx >= K * N) return;
  int n = idx / K, k = idx - n * K;
  dst[off + idx] = f2b(src[(long)k * N + n]);
}

// ---------------------------------------------------------------------------
// qc builder: qc f32 + qcb bf16 shadow
// ---------------------------------------------------------------------------
__global__ __launch_bounds__(128) void qc_kernel(
    const float* __restrict__ q, const float* __restrict__ pts,
    const float* __restrict__ Wup, const float* __restrict__ bup,
    float* __restrict__ qc, ushort* __restrict__ qcb) {
  __shared__ float xs[16][132];
  int tid = threadIdx.x;
  long row0 = (long)blockIdx.x * 16;
  for (int r = 0; r < 16; ++r) {
    long row = row0 + r;
    int b = (int)(row >> 11);
    int i = (int)(row & 2047);
    xs[r][tid] = q[((long)b * SIN + (i & 511)) * 128 + tid];
    if (tid < 2) xs[r][128 + tid] = pts[2 * i + tid];
  }
  __syncthreads();
  float acc[16];
#pragma unroll
  for (int r = 0; r < 16; ++r) acc[r] = 0.f;
  for (int k = 0; k < 130; ++k) {
    float w = Wup[k * 128 + tid];
#pragma unroll
    for (int r = 0; r < 16; ++r) acc[r] += xs[r][k] * w;
  }
  float bb = bup[tid];
#pragma unroll
  for (int r = 0; r < 16; ++r) {
    long row = row0 + r;
    float res = xs[r][tid];
    float up = fmaxf(acc[r] + bb, 0.f);
    qc[row * 256 + tid] = res;
    qc[row * 256 + 128 + tid] = up;
    qcb[row * 256 + tid] = f2b(res);
    qcb[row * 256 + 128 + tid] = f2b(up);
  }
}

// ---------------------------------------------------------------------------
// MFMA bf16 GEMM: acc = A[M,K] @ Wt[N,K]^T + bias, relu, epilogue by MODE.
//   MODE 0: bf16 row-major out            (h, l, d1)
//   MODE 1: bf16 per-batch transposed gt  (g)   [M==65536, batch=2048 rows]
//   MODE 2: f32 out2 + bf16 outv          (p1 + p1b)
//   MODE 3: f32 outv = aux - relu(acc)    (pm)
//   MODE 4: f32 outv = relu(acc) + aux    (final out)
// BM=128, BN=64, BK=64; 256 threads = 2x2 waves; wave tile 64x32.
// ---------------------------------------------------------------------------
template <int MODE>
__global__ __launch_bounds__(256) void mgemm(
    const ushort* __restrict__ A, const ushort* __restrict__ Wt,
    const float* __restrict__ bias, void* __restrict__ outv,
    float* __restrict__ out2, const float* __restrict__ aux,
    int M, int N, int K) {
  __shared__ alignas(16) ushort As[128 * 64];
  __shared__ alignas(16) ushort Bs[64 * 64];
  const int tid = threadIdx.x;
  const int w = tid >> 6, lane = tid & 63, g = lane >> 4, c = lane & 15;
  const int wm = w >> 1, wn = w & 1;
  const long row0 = (long)blockIdx.y * 128;
  const int col0 = blockIdx.x * 64;
  const long Astride = (long)K * 2;  // bytes per A row
  const char* Ab = (const char*)A;
  const char* Wb = (const char*)Wt;

  f32x4 acc[4][2];
#pragma unroll
  for (int i = 0; i < 4; ++i)
#pragma unroll
    for (int j = 0; j < 2; ++j) acc[i][j] = (f32x4){0.f, 0.f, 0.f, 0.f};

  for (int k0 = 0; k0 < K; k0 += 64) {
#pragma unroll
    for (int it = 0; it < 4; ++it) {
      int o = it * 4096 + w * 1024 + lane * 16;
      int row = o >> 7, cb = o & 127;
      gload16(Ab + (row0 + row) * Astride + k0 * 2 + (cb ^ ((row & 7) << 4)),
              (char*)As + it * 4096 + w * 1024);
    }
#pragma unroll
    for (int it = 0; it < 2; ++it) {
      int o = it * 4096 + w * 1024 + lane * 16;
      int row = o >> 7, cb = o & 127;
      gload16(Wb + (long)(col0 + row) * Astride + k0 * 2 + (cb ^ ((row & 7) << 4)),
              (char*)Bs + it * 4096 + w * 1024);
    }
    __syncthreads();
#pragma unroll
    for (int koff = 0; koff < 2; ++koff) {
      bhalf8 a[4], bfr[2];
#pragma unroll
      for (int mi = 0; mi < 4; ++mi) {
        int row = 64 * wm + 16 * mi + c;
        a[mi] = *(const bhalf8*)((const char*)As + row * 128 +
                                 ((16 * g + 64 * koff) ^ ((row & 7) << 4)));
      }
#pragma unroll
      for (int ni = 0; ni < 2; ++ni) {
        int row = 32 * wn + 16 * ni + c;
        bfr[ni] = *(const bhalf8*)((const char*)Bs + row * 128 +
                                   ((16 * g + 64 * koff) ^ ((row & 7) << 4)));
      }
#pragma unroll
      for (int mi = 0; mi < 4; ++mi)
#pragma unroll
        for (int ni = 0; ni < 2; ++ni)
          acc[mi][ni] = __builtin_amdgcn_mfma_f32_16x16x32_bf16(a[mi], bfr[ni], acc[mi][ni], 0, 0, 0);
    }
    __syncthreads();
  }

  // epilogue
#pragma unroll
  for (int ni = 0; ni < 2; ++ni) {
    int n = col0 + 32 * wn + 16 * ni + c;
    float bn = bias[n];
#pragma unroll
    for (int mi = 0; mi < 4; ++mi) {
      long m0 = row0 + 64 * wm + 16 * mi + 4 * g;
      float v[4];
#pragma unroll
      for (int r = 0; r < 4; ++r) v[r] = fmaxf(acc[mi][ni][r] + bn, 0.f);
      if (MODE == 0) {
        ushort* O = (ushort*)outv;
#pragma unroll
        for (int r = 0; r < 4; ++r) O[(m0 + r) * N + n] = f2b(v[r]);
      } else if (MODE == 1) {
        int bb = (int)(m0 >> 11);
        int ml = (int)(m0 & 2047);
        ushort4 u4;
        u4.x = f2b(v[0]); u4.y = f2b(v[1]); u4.z = f2b(v[2]); u4.w = f2b(v[3]);
        *(ushort4*)((ushort*)outv + ((long)bb * 256 + n) * 2048 + ml) = u4;
      } else if (MODE == 2) {
        ushort* O = (ushort*)outv;
#pragma unroll
        for (int r = 0; r < 4; ++r) {
          out2[(m0 + r) * N + n] = v[r];
          O[(m0 + r) * N + n] = f2b(v[r]);
        }
      } else if (MODE == 3) {
        float* O = (float*)outv;
#pragma unroll
        for (int r = 0; r < 4; ++r) O[(m0 + r) * N + n] = aux[(m0 + r) * N + n] - v[r];
      } else {
        float* O = (float*)outv;
#pragma unroll
        for (int r = 0; r < 4; ++r) O[(m0 + r) * N + n] = v[r] + aux[(m0 + r) * N + n];
      }
    }
  }
}

// ---------------------------------------------------------------------------
// MFMA flash attention v3 (occupancy-focused):
//   qcb[b,n,:] = bf16( qc[b,n,:] + softmax_m(l[n]·h[m]) @ g )
// l,h bf16 [b][2048][64]; gt bf16 [b][256][2048]; qc f32.
// LDS = P-tile only (9.2 KB). H/G fragments read directly from global (L2).
// 4 waves: QK row-split (wave w owns S rows 16w..16w+15),
// PV col-split (wave w owns O cols 64w..64w+63).
// ---------------------------------------------------------------------------
__global__ __launch_bounds__(256) void attn_kernel(
    const ushort* __restrict__ lmat, const ushort* __restrict__ hmat,
    const ushort* __restrict__ gtm, const float* __restrict__ qc,
    ushort* __restrict__ qcb) {
  __shared__ alignas(16) ushort Pt[64 * 72];
  __shared__ alignas(16) float rowscale[64];

  const int tid = threadIdx.x;
  const int w = tid >> 6, lane = tid & 63, g = lane >> 4, c = lane & 15;
  const int b = blockIdx.y, nb = blockIdx.x;

  // L (query) fragments: rows 16w+c, k = 8g + 32s
  const ushort* lrow = lmat + ((long)b * SOUT + nb * 64 + 16 * w + c) * 64 + 8 * g;
  bhalf8 la[2];
  la[0] = *(const bhalf8*)(lrow);
  la[1] = *(const bhalf8*)(lrow + 32);

  float mold[4], srow[4];
#pragma unroll
  for (int r = 0; r < 4; ++r) { mold[r] = -INFINITY; srow[r] = 0.f; }
  f32x4 oacc[4][4];
#pragma unroll
  for (int i = 0; i < 4; ++i)
#pragma unroll
    for (int t = 0; t < 4; ++t) oacc[i][t] = (f32x4){0.f, 0.f, 0.f, 0.f};

  for (int mb = 0; mb < 32; ++mb) {
    // ---- H fragments direct from global: rows 16j+c of kv block ----
    const ushort* hrow = hmat + ((long)b * SOUT + mb * 64 + c) * 64 + 8 * g;
    bhalf8 hb[4][2];
#pragma unroll
    for (int j = 0; j < 4; ++j)
#pragma unroll
      for (int s = 0; s < 2; ++s)
        hb[j][s] = *(const bhalf8*)(hrow + j * 16 * 64 + s * 32);

    // ---- QK^T ----
    f32x4 sacc[4];
#pragma unroll
    for (int j = 0; j < 4; ++j) sacc[j] = (f32x4){0.f, 0.f, 0.f, 0.f};
#pragma unroll
    for (int j = 0; j < 4; ++j)
#pragma unroll
      for (int s = 0; s < 2; ++s)
        sacc[j] = __builtin_amdgcn_mfma_f32_16x16x32_bf16(la[s], hb[j][s], sacc[j], 0, 0, 0);

    // ---- online softmax (rows 16w+4g+r) ----
    float mloc[4];
#pragma unroll
    for (int r = 0; r < 4; ++r)
      mloc[r] = fmaxf(fmaxf(sacc[0][r], sacc[1][r]), fmaxf(sacc[2][r], sacc[3][r]));
#pragma unroll
    for (int off = 1; off < 16; off <<= 1)
#pragma unroll
      for (int r = 0; r < 4; ++r)
        mloc[r] = fmaxf(mloc[r], __shfl_xor(mloc[r], off));
    float scl[4], mnew[4], psum[4];
#pragma unroll
    for (int r = 0; r < 4; ++r) {
      mnew[r] = fmaxf(mold[r], mloc[r]);
      scl[r] = __expf(mold[r] - mnew[r]);
      psum[r] = 0.f;
    }
    float pvv[4][4];
#pragma unroll
    for (int j = 0; j < 4; ++j)
#pragma unroll
      for (int r = 0; r < 4; ++r) {
        float e = __expf(sacc[j][r] - mnew[r]);
        pvv[j][r] = e; psum[r] += e;
      }
#pragma unroll
    for (int off = 1; off < 16; off <<= 1)
#pragma unroll
      for (int r = 0; r < 4; ++r) psum[r] += __shfl_xor(psum[r], off);
#pragma unroll
    for (int r = 0; r < 4; ++r) {
      srow[r] = srow[r] * scl[r] + psum[r];
      mold[r] = mnew[r];
    }

    __syncthreads();  // WAR: previous iteration's PV reads of Pt done
#pragma unroll
    for (int j = 0; j < 4; ++j)
#pragma unroll
      for (int r = 0; r < 4; ++r)
        Pt[(16 * w + 4 * g + r) * 72 + 16 * j + c] = f2b(pvv[j][r]);
    if (c == 0) {
      f32x4 s4 = {scl[0], scl[1], scl[2], scl[3]};
      *(f32x4*)&rowscale[16 * w + 4 * g] = s4;
    }
    __syncthreads();  // Pt + scales visible

    // ---- rescale O ----
#pragma unroll
    for (int i = 0; i < 4; ++i) {
      f32x4 s4 = *(const f32x4*)&rowscale[16 * i + 4 * g];
#pragma unroll
      for (int t = 0; t < 4; ++t) {
        oacc[i][t][0] *= s4[0]; oacc[i][t][1] *= s4[1];
        oacc[i][t][2] *= s4[2]; oacc[i][t][3] *= s4[3];
      }
    }

    // ---- PV: G fragments direct from global ----
    const ushort* gbase = gtm + ((long)b * 256 + 64 * w + c) * 2048 + mb * 64 + 8 * g;
#pragma unroll
    for (int s2 = 0; s2 < 2; ++s2) {
      bhalf8 pa[4];
#pragma unroll
      for (int i = 0; i < 4; ++i)
        pa[i] = *(const bhalf8*)((const char*)Pt +
                                 (16 * i + c) * 144 + 16 * g + 64 * s2);
      bhalf8 gb[4];
#pragma unroll
      for (int t = 0; t < 4; ++t)
        gb[t] = *(const bhalf8*)(gbase + (long)t * 16 * 2048 + 32 * s2);
#pragma unroll
      for (int t = 0; t < 4; ++t)
#pragma unroll
        for (int i = 0; i < 4; ++i)
          oacc[i][t] = __builtin_amdgcn_mfma_f32_16x16x32_bf16(pa[i], gb[t], oacc[i][t], 0, 0, 0);
    }
  }

  // ---- epilogue: qcb = bf16(qc + O/srow) ----
  if (c == 0) {
    f32x4 s4 = {srow[0], srow[1], srow[2], srow[3]};
    *(f32x4*)&rowscale[16 * w + 4 * g] = s4;
  }
  __syncthreads();
  long qbase = ((long)b * SOUT + nb * 64) * 256;
#pragma unroll
  for (int i = 0; i < 4; ++i) {
    f32x4 s4 = *(const f32x4*)&rowscale[16 * i + 4 * g];
#pragma unroll
    for (int r = 0; r < 4; ++r) {
      float inv = 1.0f / s4[r];
      long rb = qbase + (long)(16 * i + 4 * g + r) * 256 + 64 * w + c;
#pragma unroll
      for (int t = 0; t < 4; ++t) {
        float val = qc[rb + 16 * t] + oacc[i][t][r] * inv;
        qcb[rb + 16 * t] = f2b(val);
      }
    }
  }
}

// ---------------------------------------------------------------------------
extern "C" void kernel_launch(void* const* d_in, const int* in_sizes, int n_in,
                              void* d_out, int out_size, void* d_ws, size_t ws_size,
                              hipStream_t stream) {
  (void)in_sizes; (void)n_in; (void)out_size; (void)ws_size;
  const float* p   = (const float*)d_in[0];
  const float* Wh  = (const float*)d_in[1];
  const float* bh  = (const float*)d_in[2];
  const float* Wl  = (const float*)d_in[3];
  const float* bl  = (const float*)d_in[4];
  const float* Wg  = (const float*)d_in[5];
  const float* bg  = (const float*)d_in[6];
  const float* Wf  = (const float*)d_in[7];
  const float* bf  = (const float*)d_in[8];
  const float* Wup = (const float*)d_in[9];
  const float* bup = (const float*)d_in[10];
  const float* Wd1 = (const float*)d_in[11];
  const float* bd1 = (const float*)d_in[12];
  const float* Wd2 = (const float*)d_in[13];
  const float* bd2 = (const float*)d_in[14];
  const int* mArr  = (const int*)d_in[15];
  const int* nArr  = (const int*)d_in[16];
  float* out = (float*)d_out;

  // workspace layout (float offsets)
  float* ws    = (float*)d_ws;
  float* pts   = ws;                       // 4096
  float* qc    = ws + 4096;                // 16,777,216
  float* p1    = qc + 16777216;            //  8,388,608
  float* pm    = p1 + 8388608;             //  2,097,152
  ushort* qcb  = (ushort*)(pm + 2097152);  // 16,777,216 us
  ushort* hb   = qcb + 16777216;           //  4,194,304 us
  ushort* lb   = hb + 4194304;             //  4,194,304 us
  ushort* gt   = lb + 4194304;             // 16,777,216 us
  ushort* p1b  = gt + 16777216;            //  8,388,608 us
  ushort* d1b  = p1b + 8388608;            //  4,194,304 us
  ushort* wts  = d1b + 4194304;            //   294,912 us
  ushort* Wht  = wts;
  ushort* Wlt  = wts + 16384;
  ushort* Wgt  = wts + 32768;
  ushort* Wft  = wts + 98304;
  ushort* Wd1t = wts + 131072;
  ushort* Wd2t = wts + 262144;

  pts_kernel<<<8, 256, 0, stream>>>(mArr, nArr, pts);
  wconv_kernel<<<dim3(512, 6), 256, 0, stream>>>(Wh, Wl, Wg, Wf, Wd1, Wd2, wts);

  // ---------------- up #1 ----------------
  qc_kernel<<<4096, 128, 0, stream>>>(p, pts, Wup, bup, qc, qcb);
  mgemm<0><<<dim3(1, 512), 256, 0, stream>>>(qcb, Wht, bh, hb, nullptr, nullptr, 65536, 64, 256);
  mgemm<0><<<dim3(1, 512), 256, 0, stream>>>(qcb, Wlt, bl, lb, nullptr, nullptr, 65536, 64, 256);
  mgemm<1><<<dim3(4, 512), 256, 0, stream>>>(qcb, Wgt, bg, gt, nullptr, nullptr, 65536, 256, 256);
  attn_kernel<<<dim3(32, 32), 256, 0, stream>>>(lb, hb, gt, qc, qcb);
  mgemm<2><<<dim3(2, 512), 256, 0, stream>>>(qcb, Wft, bf, p1b, p1, nullptr, 65536, 128, 256);

  // ---------------- down ----------------
  mgemm<0><<<dim3(4, 128), 256, 0, stream>>>(p1b, Wd1t, bd1, d1b, nullptr, nullptr, 16384, 256, 512);
  mgemm<3><<<dim3(2, 128), 256, 0, stream>>>(d1b, Wd2t, bd2, pm, nullptr, p, 16384, 128, 256);

  // ---------------- up #2 + final add ----------------
  qc_kernel<<<4096, 128, 0, stream>>>(pm, pts, Wup, bup, qc, qcb);
  mgemm<0><<<dim3(1, 512), 256, 0, stream>>>(qcb, Wht, bh, hb, nullptr, nullptr, 65536, 64, 256);
  mgemm<0><<<dim3(1, 512), 256, 0, stream>>>(qcb, Wlt, bl, lb, nullptr, nullptr, 65536, 64, 256);
  mgemm<1><<<dim3(4, 512), 256, 0, stream>>>(qcb, Wgt, bg, gt, nullptr, nullptr, 65536, 256, 256);
  attn_kernel<<<dim3(32, 32), 256, 0, stream>>>(lb, hb, gt, qc, qcb);
  mgemm<4><<<dim3(2, 512), 256, 0, stream>>>(qcb, Wft, bf, out, nullptr, p1, 65536, 128, 256);
}